// Round 18
// baseline (26.133 us; speedup 1.0000x reference)
//
#include <hip/hip_runtime.h>

typedef __attribute__((ext_vector_type(8))) short bf16x8;
typedef __attribute__((ext_vector_type(4))) float f32x4;

union FragU { uint4 q; bf16x8 h; };

__device__ __forceinline__ unsigned short f2bf(float f) {
  unsigned u = __float_as_uint(f);
  u += 0x7FFFu + ((u >> 16) & 1u);   // RNE
  return (unsigned short)(u >> 16);
}
__device__ __forceinline__ unsigned pack2(float lo, float hi) {
  return (unsigned)f2bf(lo) | ((unsigned)f2bf(hi) << 16);
}

// ---------------------------------------------------------------------------
// kX: cast x into MFMA B-fragment layout (r8-proven mapping), xbf only.
// Grid 128 x 1024 = 131072 units, 1/thread.
// ---------------------------------------------------------------------------
__global__ __launch_bounds__(1024) void kX(
    const float* __restrict__ x, uint4* __restrict__ xbf)
{
  const int u = blockIdx.x * 1024 + threadIdx.x;
  const int l = u & 63, c = (u >> 6) & 7, t = (u >> 9) & 15, b = u >> 13;
  const int fr = l & 15, fq = l >> 4;
  const float* p = x + (size_t)((b * 16 + t) * 16 + fr) * 256 + c * 32 + fq * 8;
  float4 va = *(const float4*)p;
  float4 vb = *(const float4*)(p + 4);
  xbf[u] = make_uint4(pack2(va.x, va.y), pack2(va.z, va.w),
                      pack2(vb.x, vb.y), pack2(vb.z, vb.w));
}

// ---------------------------------------------------------------------------
// kA: block (b, hc), 1024 thr = 16 waves, all waves active in every phase.
//  p0 : afr gather-cast from native W1 (r14 kX formula, r11-proven pattern).
//  p1 : wave wv = m-tile wv: 8 MFMA -> As[8][m] (a), Cs[8][m] (c + b1).
//  p1.5: wave (hp=wv&7, half=wv>>3) bitonic-sorts Cs[hp][half*128..+128]
//        (2 regs/lane, 21 cross-lane stages) + suffix scan; exports
//        sortedC, 8 pivots + 8 block-suffix-sums per half.
//  p2 : wave (hp, mq): 2x64 m. Per m: search BOTH halves independently
//        (8 pivot compares + 16-leaf scan each), cnt/S add across halves.
//        Exact: sum_k2 relu(a+c) = cnt*a + S.
//  p3 : tid<256 packs mh row into kB fragment layout (r15-verbatim).
// Grid (16,16) = 256 blocks, ~26 KB LDS.
// ---------------------------------------------------------------------------
__global__ __launch_bounds__(1024) void kA(
    const uint4* __restrict__ xbf, const float* __restrict__ W1,
    const float* __restrict__ b1, uint4* __restrict__ mf)
{
  __shared__ float Cs[8][260];
  __shared__ float As[8][260];      // a-values; overwritten in-place by mh
  __shared__ float sortedC[8][256];
  __shared__ float Piv[8][16];      // [hp][half*8 + j]
  __shared__ float sufBlk[8][16];   // [hp][half*8 + j]: suffix from block j+1

  const int tid = threadIdx.x, lane = tid & 63, wv = tid >> 6;  // wv 0..15
  const int b = blockIdx.x, hc = blockIdx.y;
  const int fr = lane & 15, fq = lane >> 4;

  // ---- p0: A-frags from native W1 ----
  const float* __restrict__ wp =
      W1 + (size_t)((fr >= 8) ? 256 : 0) * 128 + hc * 8 + (fr & 7);
  FragU afr[8];
#pragma unroll
  for (int c = 0; c < 8; ++c) {
    float v[8];
#pragma unroll
    for (int j = 0; j < 8; ++j) v[j] = wp[(size_t)(c * 32 + fq * 8 + j) * 128];
    afr[c].q = make_uint4(pack2(v[0], v[1]), pack2(v[2], v[3]),
                          pack2(v[4], v[5]), pack2(v[6], v[7]));
  }

  float b1v[4];
#pragma unroll
  for (int g = 0; g < 4; ++g)
    b1v[g] = (fq >= 2) ? b1[hc * 8 + (fq - 2) * 4 + g] : 0.f;

  // ---- p1: MFMA, wave = m-tile (r15-verbatim) ----
  {
    const int t = wv;
    f32x4 acc = {0.f, 0.f, 0.f, 0.f};
#pragma unroll
    for (int c = 0; c < 8; ++c) {
      FragU bfr;
      bfr.q = xbf[((size_t)(b * 16 + t) * 8 + c) * 64 + lane];
      acc = __builtin_amdgcn_mfma_f32_16x16x32_bf16(afr[c].h, bfr.h, acc, 0, 0, 0);
    }
    const int m = t * 16 + fr;
    if (fq < 2) {
#pragma unroll
      for (int g = 0; g < 4; ++g) As[fq * 4 + g][m] = acc[g];
    } else {
#pragma unroll
      for (int g = 0; g < 4; ++g) Cs[(fq - 2) * 4 + g][m] = acc[g] + b1v[g];
    }
  }
  __syncthreads();

  // ---- p1.5: wave (hp, half) sorts its 128 c-values (2 regs/lane) ----
  {
    const int hp = wv & 7, half = wv >> 3;
    const int base = half * 128;
    float v0 = Cs[hp][base + lane * 2 + 0];
    float v1 = Cs[hp][base + lane * 2 + 1];

#define CE2(X, Y, UP)                                     \
    {                                                     \
      float mn = fminf(X, Y), mx = fmaxf(X, Y);           \
      X = (UP) ? mn : mx;  Y = (UP) ? mx : mn;            \
    }
    { const bool up = (lane & 1) == 0; CE2(v0, v1, up) }   // k=2
#pragma unroll
    for (int k2 = 2; k2 <= 64; k2 <<= 1) {                 // k = 4..128
      const bool up = (lane & k2) == 0;
#pragma unroll
      for (int j2 = k2 >> 1; j2 >= 1; j2 >>= 1) {          // cross-lane j=2*j2
        const bool keepMin = (((lane & j2) == 0) == up);
#define CEX(V)                                            \
        {                                                 \
          float o = __shfl_xor(V, j2, 64);                \
          V = keepMin ? fminf(V, o) : fmaxf(V, o);        \
        }
        CEX(v0) CEX(v1)
#undef CEX
      }
      CE2(v0, v1, up)                                      // j=1 (in-lane)
    }
#undef CE2

    // suffix sums within the half
    const float sl = v0 + v1;
    float inc = sl;
#pragma unroll
    for (int off = 1; off < 64; off <<= 1) {
      float t = __shfl_down(inc, off, 64);
      inc += (lane + off < 64) ? t : 0.f;
    }
    const float T = inc - sl;       // suffix strictly above this lane
    const float su1 = T + v1;
    const float su0 = su1 + v0;     // suffix from e = lane*2

    sortedC[hp][base + lane * 2 + 0] = v0;
    sortedC[hp][base + lane * 2 + 1] = v1;
    // block j (16 elems): pivot = e[16j+15] -> lane 8j+7, reg v1
    if ((lane & 7) == 7) Piv[hp][half * 8 + (lane >> 3)] = v1;
    // sufBlk[j] = suffix from e=16(j+1) -> su0 of lane 8(j+1)
    if ((lane & 7) == 0 && lane) sufBlk[hp][half * 8 + (lane >> 3) - 1] = su0;
    if (lane == 0) sufBlk[hp][half * 8 + 7] = 0.f;
  }
  __syncthreads();

  // ---- p2: dual-half search; wave (hp = wv&7, mq = wv>>3), 2x64 m ----
  {
    const int hp = wv & 7, mq = wv >> 3;
    float piv[16];
#pragma unroll
    for (int j = 0; j < 16; j += 4) {     // broadcast reads (uniform addr)
      float4 pv = *(const float4*)&Piv[hp][j];
      piv[j] = pv.x; piv[j + 1] = pv.y; piv[j + 2] = pv.z; piv[j + 3] = pv.w;
    }
#pragma unroll
    for (int q = 0; q < 2; ++q) {
      const int m = mq * 128 + q * 64 + lane;
      const float a = As[hp][m];
      const float t = -a;
      int p0 = 0, p1 = 0;
#pragma unroll
      for (int j = 0; j < 8; ++j) {
        p0 += (piv[j] <= t) ? 1 : 0;
        p1 += (piv[8 + j] <= t) ? 1 : 0;
      }
      p0 = (p0 > 7) ? 7 : p0;
      p1 = (p1 > 7) ? 7 : p1;
      const float Sb0 = sufBlk[hp][p0];
      const float Sb1 = sufBlk[hp][8 + p1];
      const float* leaf0 = &sortedC[hp][p0 * 16];
      const float* leaf1 = &sortedC[hp][128 + p1 * 16];
      float sum0 = 0.f, sum1 = 0.f; int cnt0 = 0, cnt1 = 0;
#pragma unroll
      for (int j = 0; j < 16; j += 4) {
        float4 l0 = *(const float4*)&leaf0[j];
        float4 l1 = *(const float4*)&leaf1[j];
        if (l0.x > t) { sum0 += l0.x; ++cnt0; }
        if (l0.y > t) { sum0 += l0.y; ++cnt0; }
        if (l0.z > t) { sum0 += l0.z; ++cnt0; }
        if (l0.w > t) { sum0 += l0.w; ++cnt0; }
        if (l1.x > t) { sum1 += l1.x; ++cnt1; }
        if (l1.y > t) { sum1 += l1.y; ++cnt1; }
        if (l1.z > t) { sum1 += l1.z; ++cnt1; }
        if (l1.w > t) { sum1 += l1.w; ++cnt1; }
      }
      const float cnt = (float)((112 - 16 * p0 + cnt0) + (112 - 16 * p1 + cnt1));
      const float S = (Sb0 + sum0) + (Sb1 + sum1);
      As[hp][m] = (cnt * a + S) * (1.f / 256.f);
    }
  }
  __syncthreads();

  // ---- p3: pack row m=tid into kB fragment layout (r15-verbatim) ----
  if (tid < 256) {
    const int fr2 = tid & 15, T2 = tid >> 4;
    uint4 o = make_uint4(pack2(As[0][tid], As[1][tid]), pack2(As[2][tid], As[3][tid]),
                         pack2(As[4][tid], As[5][tid]), pack2(As[6][tid], As[7][tid]));
    mf[((size_t)(b * 16 + T2) * 4 + (hc >> 2)) * 64 + (hc & 3) * 16 + fr2] = o;
  }
}

// ---------------------------------------------------------------------------
// kB: out[m][d] = mh@W2 + b2 + x.  A = mf fragments; B gather-cast from
// native W2 (r11-proven). 256 blocks x 1024 thr, wave = d-group.
// ---------------------------------------------------------------------------
__global__ __launch_bounds__(1024) void kB(
    const uint4* __restrict__ mf, const float* __restrict__ W2,
    const float* __restrict__ b2, const float* __restrict__ x,
    float* __restrict__ out)
{
  const int tid = threadIdx.x, lane = tid & 63, wu = tid >> 6;
  const int mt = blockIdx.x;     // 0..255
  const int dg = wu;             // 0..15
  const int fr = lane & 15, fq = lane >> 4;

  const float* __restrict__ w2p = W2 + dg * 16 + fr;
  FragU bfr[4];
#pragma unroll
  for (int c = 0; c < 4; ++c) {
    float v[8];
#pragma unroll
    for (int j = 0; j < 8; ++j) v[j] = w2p[(size_t)(c * 32 + fq * 8 + j) * 256];
    bfr[c].q = make_uint4(pack2(v[0], v[1]), pack2(v[2], v[3]),
                          pack2(v[4], v[5]), pack2(v[6], v[7]));
  }

  f32x4 acc = {0.f, 0.f, 0.f, 0.f};
#pragma unroll
  for (int c = 0; c < 4; ++c) {
    FragU a;
    a.q = mf[((size_t)mt * 4 + c) * 64 + lane];
    acc = __builtin_amdgcn_mfma_f32_16x16x32_bf16(a.h, bfr[c].h, acc, 0, 0, 0);
  }

  const int d = dg * 16 + fr;
  const float bv = b2[d];
#pragma unroll
  for (int g = 0; g < 4; ++g) {
    const int m = mt * 16 + fq * 4 + g;
    const size_t o = (size_t)m * 256 + d;
    out[o] = acc[g] + bv + x[o];
  }
}

extern "C" void kernel_launch(void* const* d_in, const int* in_sizes, int n_in,
                              void* d_out, int out_size, void* d_ws, size_t ws_size,
                              hipStream_t stream) {
  const float* x  = (const float*)d_in[0];
  const float* W1 = (const float*)d_in[1];
  const float* b1 = (const float*)d_in[2];
  const float* W2 = (const float*)d_in[3];
  const float* b2 = (const float*)d_in[4];
  float* out = (float*)d_out;

  char* ws = (char*)d_ws;
  uint4* xbf = (uint4*)ws;                 // 131072 units = 2 MB
  uint4* mf  = (uint4*)(ws + (2u << 20));  // 65536 units = 1 MB

  kX<<<128, 1024, 0, stream>>>(x, xbf);
  kA<<<dim3(16, 16), 1024, 0, stream>>>(xbf, W1, b1, mf);
  kB<<<256, 1024, 0, stream>>>(mf, W2, b2, x, out);
}

// Round 19
// 21.480 us; speedup vs baseline: 1.2166x; 1.2166x over previous
//
#include <hip/hip_runtime.h>

typedef __attribute__((ext_vector_type(8))) short bf16x8;
typedef __attribute__((ext_vector_type(4))) float f32x4;

union FragU { uint4 q; bf16x8 h; };

__device__ __forceinline__ unsigned short f2bf(float f) {
  unsigned u = __float_as_uint(f);
  u += 0x7FFFu + ((u >> 16) & 1u);   // RNE
  return (unsigned short)(u >> 16);
}
__device__ __forceinline__ unsigned pack2(float lo, float hi) {
  return (unsigned)f2bf(lo) | ((unsigned)f2bf(hi) << 16);
}

// ---------------------------------------------------------------------------
// kX (r8-verbatim): one-shot cast into MFMA-fragment layouts.
// ---------------------------------------------------------------------------
__global__ __launch_bounds__(256) void kX(
    const float* __restrict__ x, const float* __restrict__ W1,
    const float* __restrict__ W2, uint4* __restrict__ xbf,
    uint4* __restrict__ w1f, uint4* __restrict__ w2f)
{
  const int u = blockIdx.x * 256 + threadIdx.x;
  if (u < 131072) {            // x frags: 16b x 16t x 8c x 64l
    const int l = u & 63, c = (u >> 6) & 7, t = (u >> 9) & 15, b = u >> 13;
    const int fr = l & 15, fq = l >> 4;
    const float* p = x + (size_t)((b * 16 + t) * 16 + fr) * 256 + c * 32 + fq * 8;
    float4 va = *(const float4*)p;
    float4 vb = *(const float4*)(p + 4);
    xbf[u] = make_uint4(pack2(va.x, va.y), pack2(va.z, va.w),
                        pack2(vb.x, vb.y), pack2(vb.z, vb.w));
  } else if (u < 139264) {     // W1 frags: 16hc x 8c x 64l
    const int u2 = u - 131072;
    const int l = u2 & 63, c = (u2 >> 6) & 7, hc = u2 >> 9;
    const int fr = l & 15, fq = l >> 4;
    const float* p = W1 + (size_t)((fr >= 8) ? 256 : 0) * 128 +
                     (size_t)(c * 32 + fq * 8) * 128 + hc * 8 + (fr & 7);
    float v[8];
#pragma unroll
    for (int j = 0; j < 8; ++j) v[j] = p[(size_t)j * 128];
    w1f[u2] = make_uint4(pack2(v[0], v[1]), pack2(v[2], v[3]),
                         pack2(v[4], v[5]), pack2(v[6], v[7]));
  } else if (u < 143360) {     // W2 frags: 16dg x 4c x 64l
    const int u3 = u - 139264;
    const int l = u3 & 63, c = (u3 >> 6) & 3, dg = u3 >> 8;
    const int fr = l & 15, fq = l >> 4;
    const float* p = W2 + (size_t)(c * 32 + fq * 8) * 256 + dg * 16 + fr;
    float v[8];
#pragma unroll
    for (int j = 0; j < 8; ++j) v[j] = p[(size_t)j * 256];
    w2f[u3] = make_uint4(pack2(v[0], v[1]), pack2(v[2], v[3]),
                         pack2(v[4], v[5]), pack2(v[6], v[7]));
  }
}

// ---------------------------------------------------------------------------
// kA: phases 0/1/3 r14-verbatim.  Phase 1.5+2: sort-based pairwise.
//   1.5: wave wv<8 bitonic-sorts Cs[wv][0..255] in registers (4 elems/lane),
//        suffix-scan, store sortedC + sufS.
//   2:   16 waves x 64 lanes x 2 m: binary search idx = #{c <= -a} (8 LDS
//        probes), mh = ((256-idx)*a + sufS[idx]) / 256  [exact relu-sum].
// Block (b, hc), 1024 thr = 16 waves. Grid (16,16).
// ---------------------------------------------------------------------------
__global__ __launch_bounds__(1024) void kA(
    const uint4* __restrict__ xbf, const uint4* __restrict__ w1f,
    const float* __restrict__ b1, uint4* __restrict__ mf)
{
  __shared__ float Cs[8][260];
  __shared__ float As[8][260];      // a-values; overwritten in-place by mh
  __shared__ float sortedC[8][256];
  __shared__ float sufS[8][260];    // suffix sums; sufS[hp][256] = 0

  const int tid = threadIdx.x, lane = tid & 63, wv = tid >> 6;  // wv 0..15
  const int b = blockIdx.x, hc = blockIdx.y;
  const int fr = lane & 15, fq = lane >> 4;

  FragU afr[8];
#pragma unroll
  for (int c = 0; c < 8; ++c) afr[c].q = w1f[(hc * 8 + c) * 64 + lane];

  float b1v[4];
#pragma unroll
  for (int g = 0; g < 4; ++g)
    b1v[g] = (fq >= 2) ? b1[hc * 8 + (fq - 2) * 4 + g] : 0.f;

  {  // ---- phase 1: MFMA, wave = m-tile (r14-verbatim) ----
    const int t = wv;
    f32x4 acc = {0.f, 0.f, 0.f, 0.f};
#pragma unroll
    for (int c = 0; c < 8; ++c) {
      FragU bfr;
      bfr.q = xbf[((size_t)(b * 16 + t) * 8 + c) * 64 + lane];
      acc = __builtin_amdgcn_mfma_f32_16x16x32_bf16(afr[c].h, bfr.h, acc, 0, 0, 0);
    }
    const int m = t * 16 + fr;
    if (fq < 2) {
#pragma unroll
      for (int g = 0; g < 4; ++g) As[fq * 4 + g][m] = acc[g];
    } else {
#pragma unroll
      for (int g = 0; g < 4; ++g) Cs[(fq - 2) * 4 + g][m] = acc[g] + b1v[g];
    }
  }
  __syncthreads();

  // ---- phase 1.5: waves 0..7 sort Cs[wv] (bitonic, 4 regs/lane) ----
  if (wv < 8) {
    const int hp = wv;
    float v0 = Cs[hp][lane * 4 + 0], v1 = Cs[hp][lane * 4 + 1];
    float v2 = Cs[hp][lane * 4 + 2], v3 = Cs[hp][lane * 4 + 3];

#define CE2(X, Y, UP)                                     \
    {                                                     \
      float mn = fminf(X, Y), mx = fmaxf(X, Y);           \
      X = (UP) ? mn : mx;  Y = (UP) ? mx : mn;            \
    }
    // k=2
    CE2(v0, v1, true) CE2(v2, v3, false)
    // k=4
    {
      const bool up4 = (lane & 1) == 0;
      CE2(v0, v2, up4) CE2(v1, v3, up4)
      CE2(v0, v1, up4) CE2(v2, v3, up4)
    }
    // k = 8..256  (k4 = k/4)
#pragma unroll
    for (int k4 = 2; k4 <= 64; k4 <<= 1) {
      const bool up = (lane & k4) == 0;
#pragma unroll
      for (int j4 = k4 >> 1; j4 >= 1; j4 >>= 1) {   // cross-lane j = 4*j4
        const bool keepMin = (((lane & j4) == 0) == up);
#define CEX(V)                                            \
        {                                                 \
          float o = __shfl_xor(V, j4, 64);                \
          V = keepMin ? fminf(V, o) : fmaxf(V, o);        \
        }
        CEX(v0) CEX(v1) CEX(v2) CEX(v3)
#undef CEX
      }
      CE2(v0, v2, up) CE2(v1, v3, up)   // j=2
      CE2(v0, v1, up) CE2(v2, v3, up)   // j=1
    }
#undef CE2

    // suffix sums: T = sum over higher lanes, then in-lane suffix
    const float sl = (v0 + v1) + (v2 + v3);
    float inc = sl;
#pragma unroll
    for (int off = 1; off < 64; off <<= 1) {
      float t = __shfl_down(inc, off, 64);
      inc += (lane + off < 64) ? t : 0.f;
    }
    const float T = inc - sl;          // suffix strictly above this lane
    const float su3 = T + v3;
    const float su2 = su3 + v2;
    const float su1 = su2 + v1;
    const float su0 = su1 + v0;
    sortedC[hp][lane * 4 + 0] = v0;
    sortedC[hp][lane * 4 + 1] = v1;
    sortedC[hp][lane * 4 + 2] = v2;
    sortedC[hp][lane * 4 + 3] = v3;
    sufS[hp][lane * 4 + 0] = su0;
    sufS[hp][lane * 4 + 1] = su1;
    sufS[hp][lane * 4 + 2] = su2;
    sufS[hp][lane * 4 + 3] = su3;
    if (lane == 0) sufS[hp][256] = 0.f;
  }
  __syncthreads();

  // ---- phase 2: binary search; wave (hp = wv&7, half = wv>>3), 2 m each ----
  {
    const int hp = wv & 7, half = wv >> 3;
#pragma unroll
    for (int q = 0; q < 2; ++q) {
      const int m = half * 128 + q * 64 + lane;
      const float a = As[hp][m];
      const float t = -a;
      int idx = 0;
#pragma unroll
      for (int st = 128; st >= 1; st >>= 1)
        idx += (sortedC[hp][idx + st - 1] <= t) ? st : 0;
      const float cnt = (float)(256 - idx);
      const float S = sufS[hp][idx];
      As[hp][m] = (cnt * a + S) * (1.f / 256.f);
    }
  }
  __syncthreads();

  // ---- phase 3: pack row m=tid into kB fragment layout (r14-verbatim) ----
  if (tid < 256) {
    const int fr2 = tid & 15, T2 = tid >> 4;
    uint4 o = make_uint4(pack2(As[0][tid], As[1][tid]), pack2(As[2][tid], As[3][tid]),
                         pack2(As[4][tid], As[5][tid]), pack2(As[6][tid], As[7][tid]));
    mf[((size_t)(b * 16 + T2) * 4 + (hc >> 2)) * 64 + (hc & 3) * 16 + fr2] = o;
  }
}

// ---------------------------------------------------------------------------
// kB (r8-verbatim): out[m][d] = mh@W2 + b2 + x. Grid (256,4) x 256 thr.
// ---------------------------------------------------------------------------
__global__ __launch_bounds__(256) void kB(
    const uint4* __restrict__ mf, const uint4* __restrict__ w2f,
    const float* __restrict__ b2, const float* __restrict__ x,
    float* __restrict__ out)
{
  const int tid = threadIdx.x, lane = tid & 63, wu = tid >> 6;
  const int mt = blockIdx.x;
  const int dg = blockIdx.y * 4 + wu;
  const int fr = lane & 15, fq = lane >> 4;

  f32x4 acc = {0.f, 0.f, 0.f, 0.f};
#pragma unroll
  for (int c = 0; c < 4; ++c) {
    FragU a, bb;
    a.q  = mf[((size_t)mt * 4 + c) * 64 + lane];
    bb.q = w2f[((size_t)dg * 4 + c) * 64 + lane];
    acc = __builtin_amdgcn_mfma_f32_16x16x32_bf16(a.h, bb.h, acc, 0, 0, 0);
  }

  const int d = dg * 16 + fr;
  const float bv = b2[d];
#pragma unroll
  for (int g = 0; g < 4; ++g) {
    const int m = mt * 16 + fq * 4 + g;
    const size_t o = (size_t)m * 256 + d;
    out[o] = acc[g] + bv + x[o];
  }
}

extern "C" void kernel_launch(void* const* d_in, const int* in_sizes, int n_in,
                              void* d_out, int out_size, void* d_ws, size_t ws_size,
                              hipStream_t stream) {
  const float* x  = (const float*)d_in[0];
  const float* W1 = (const float*)d_in[1];
  const float* b1 = (const float*)d_in[2];
  const float* W2 = (const float*)d_in[3];
  const float* b2 = (const float*)d_in[4];
  float* out = (float*)d_out;

  char* ws = (char*)d_ws;
  uint4* xbf = (uint4*)ws;                               // 131072 u = 2 MB
  uint4* w1f = (uint4*)(ws + (2u << 20));                // 8192 u = 128 KB
  uint4* w2f = (uint4*)(ws + (2u << 20) + (128u << 10)); // 4096 u = 64 KB
  uint4* mf  = (uint4*)(ws + (2u << 20) + (192u << 10)); // 65536 u = 1 MB

  kX<<<560, 256, 0, stream>>>(x, W1, W2, xbf, w1f, w2f);
  kA<<<dim3(16, 16), 1024, 0, stream>>>(xbf, w1f, b1, mf);
  kB<<<dim3(256, 4), 256, 0, stream>>>(mf, w2f, b2, x, out);
}